// Round 6
// baseline (307.077 us; speedup 1.0000x reference)
//
#include <hip/hip_runtime.h>

// ---------------------------------------------------------------------------
// VM-LSTM cell, B=8192, D=H=1024, G=2, WR=64, URANKS=[64,64]
//
//   prep : frag-major fp16 stage-1 weights (U1f, Uh1f), stage-2 W2f;
//          correction vectors cx/ch/bb via one wave per (q,k) + shfl reduce.
//   s1   : 16-row blocks, grid (512,3); writes MERGED T (320 cols/row):
//          [0:64)   = x@Ux        (shared by both halves)
//          [64:192) = h-part for gates i,f   (old Ta cols 64..191)
//          [192:320)= h-part for gates o,n   (old Tb cols 64..191)
//   s2   : 32-row x 128-col blocks, grid (256,8); merged-T staged once to
//          LDS (21 KB); epilogue x/h/c prefetched before MFMA chain;
//          B-frags coalesced from W2f; rcp-based LSTM epilogue.
// Gates: sg=0 i, 1 f (A-half); 2 o, 3 n (B-half). jx(q)=q, jh(q)=q^1.
// ---------------------------------------------------------------------------

typedef _Float16 half8 __attribute__((ext_vector_type(8)));
typedef _Float16 half4v __attribute__((ext_vector_type(4)));
typedef float f32x4 __attribute__((ext_vector_type(4)));

// workspace offsets (bytes)
#define WS_TM    0                     // 8192*320 fp16 = 5242880
#define WS_U1F   5242880               // 131072
#define WS_UH1F  5373952               // 262144
#define WS_W2    5636096               // 1572864 (frag-major)
#define WS_CX    7208960               // 4096 fp32
#define WS_CH    7225344
#define WS_BB    7241728

// ---------------------------------------------------------------------------
__global__ __launch_bounds__(256) void prep_kernel(
    const float* __restrict__ Ux, const float* __restrict__ Vx,
    const float* __restrict__ Uh0, const float* __restrict__ Vh0,
    const float* __restrict__ Uh1, const float* __restrict__ Vh1,
    const float* __restrict__ dia_x, const float* __restrict__ dia_h,
    const float* __restrict__ bias_x, const float* __restrict__ bias_h,
    _Float16* __restrict__ U1f, _Float16* __restrict__ Uh1f,
    _Float16* __restrict__ W2f, float* __restrict__ cx,
    float* __restrict__ ch, float* __restrict__ bb)
{
    int e = blockIdx.x * 256 + threadIdx.x;
    if (e < 8192) {
        // U1f[ct(4)][ks(32)][lane][8]: B-frag for x@Ux.
        int lane = e & 63, ks = (e >> 6) & 31, ct = e >> 11;
        int l15 = lane & 15, quad = lane >> 4;
        half8 v8;
        #pragma unroll
        for (int jj = 0; jj < 8; ++jj) {
            int k = ks * 32 + quad * 8 + jj;
            v8[jj] = (_Float16)Ux[k * 64 + ct * 16 + l15];
        }
        *(half8*)&U1f[(size_t)e * 8] = v8;
    } else if (e < 24576) {
        // Uh1f[j(4)][ct(4)][ks(16)][lane][8]; j: 0=Uh0g0,1=Uh1g0,2=Uh0g1,3=Uh1g1
        int t = e - 8192;
        int lane = t & 63, ks = (t >> 6) & 15, ct = (t >> 10) & 3, j = t >> 12;
        int l15 = lane & 15, quad = lane >> 4;
        const float* src = (j & 1) ? Uh1 : Uh0;
        int g = j >> 1;
        half8 v8;
        #pragma unroll
        for (int jj = 0; jj < 8; ++jj) {
            int k = ks * 32 + quad * 8 + jj;
            v8[jj] = (_Float16)src[(g * 512 + k) * 64 + ct * 16 + l15];
        }
        *(half8*)&Uh1f[(size_t)t * 8] = v8;
    } else if (e < 122880) {
        // W2f fragment-major: t = (((s*2+g01)*64 + ct)*6 + ks)*64 + lane
        int t = e - 24576;                 // 0..98303
        int lane = t & 63;
        int ksq  = (t >> 6) % 6;
        int ct   = (t / 384) & 63;
        int g01  = (t / 24576) & 1;
        int s    = t / 49152;
        int l15 = lane & 15, quad = lane >> 4;
        int k = ct * 16 + l15;             // output column
        int jx = s * 2 + g01;
        int m = (g01 == 0) ? (1024 + k) : k;
        half8 v8;
        #pragma unroll
        for (int jj = 0; jj < 8; ++jj) {
            int kk = ksq * 32 + quad * 8 + jj;   // K index 0..191
            int r = kk & 63, sect = kk >> 6;
            float val;
            if (sect == 0)      val = Vx[(jx * 1024 + k) * 64 + r];
            else if (sect == 1) val = Vh0[(s * 64 + r) * 2048 + m];
            else                val = Vh1[(s * 64 + r) * 2048 + m];
            v8[jj] = (_Float16)val;
        }
        *(half8*)&W2f[(size_t)t * 8] = v8;
    } else if (e < 385024) {
        // correction vectors: ONE WAVE per (q,k), lane = rank r, shfl reduce.
        // (R5: 4096 threads x 64-iter serial loop on 16 blocks was a straggler)
        int t = e - 122880;
        int r = t & 63;
        int wid = t >> 6;                  // 0..4095  (q*1024 + k)
        int q = wid >> 10, k = wid & 1023;
        int jh = q ^ 1;
        int fh = jh * 1024 + k; int g = fh >> 11; int m = fh & 2047;
        float sx = Ux[k * 64 + r] * Vx[(q * 1024 + k) * 64 + r];
        float sh = Uh0[k * 64 + r] * Vh0[(g * 64 + r) * 2048 + m];
        #pragma unroll
        for (int msk = 1; msk < 64; msk <<= 1) {
            sx += __shfl_xor(sx, msk, 64);
            sh += __shfl_xor(sh, msk, 64);
        }
        if (r == 0) {
            cx[wid] = dia_x[k] - sx;
            ch[wid] = dia_h[k] - sh;
            bb[wid] = bias_x[q * 1024 + k] + bias_h[jh * 1024 + k];
        }
    }
}

// ---------------------------------------------------------------------------
// Stage 1: 16-row blocks, grid (512,3); writes merged T (stride 320).
__global__ __launch_bounds__(256) void s1_kernel(
    const float* __restrict__ x, const float* __restrict__ h,
    const _Float16* __restrict__ U1f, const _Float16* __restrict__ Uh1f,
    _Float16* __restrict__ Tm)
{
    __shared__ __align__(16) _Float16 Ash[16][520];

    const int job = blockIdx.y;
    const int b0 = blockIdx.x * 16;
    const int tid = threadIdx.x;
    const int w = tid >> 6, l = tid & 63, l15 = l & 15, quad = l >> 4;

    f32x4 acc0 = {}, acc1 = {};
    const int nkc = (job == 0) ? 2 : 1;
    const float* src = (job == 0) ? x : h;

    for (int kc = 0; kc < nkc; ++kc) {
        const int koff = (job == 2) ? 512 : kc * 512;
        #pragma unroll
        for (int ii = 0; ii < 8; ++ii) {
            int idx = tid + ii * 256;      // 0..2047
            int row = idx >> 7, c4 = idx & 127;
            float4 f = *(const float4*)&src[(size_t)(b0 + row) * 1024 + koff + c4 * 4];
            half4v p;
            p[0] = (_Float16)f.x; p[1] = (_Float16)f.y;
            p[2] = (_Float16)f.z; p[3] = (_Float16)f.w;
            *(half4v*)&Ash[row][c4 * 4] = p;
        }
        __syncthreads();
        if (job == 0) {
            const _Float16* bp = U1f + ((size_t)(w * 32 + kc * 16) * 64 + l) * 8;
            #pragma unroll
            for (int ks = 0; ks < 16; ++ks) {
                half8 a = *(const half8*)&Ash[l15][ks * 32 + quad * 8];
                half8 b = *(const half8*)(bp + (size_t)ks * 512);
                acc0 = __builtin_amdgcn_mfma_f32_16x16x32_f16(a, b, acc0, 0, 0, 0);
            }
        } else {
            const int j0 = (job == 1) ? 0 : 1;   // -> A-half
            const int j1 = (job == 1) ? 3 : 2;   // -> B-half
            const _Float16* bp0 = Uh1f + ((size_t)((j0 * 4 + w) * 16) * 64 + l) * 8;
            const _Float16* bp1 = Uh1f + ((size_t)((j1 * 4 + w) * 16) * 64 + l) * 8;
            #pragma unroll
            for (int ks = 0; ks < 16; ++ks) {
                half8 a = *(const half8*)&Ash[l15][ks * 32 + quad * 8];
                half8 b0 = *(const half8*)(bp0 + (size_t)ks * 512);
                acc0 = __builtin_amdgcn_mfma_f32_16x16x32_f16(a, b0, acc0, 0, 0, 0);
                half8 b1 = *(const half8*)(bp1 + (size_t)ks * 512);
                acc1 = __builtin_amdgcn_mfma_f32_16x16x32_f16(a, b1, acc1, 0, 0, 0);
            }
        }
        __syncthreads();
    }
    if (job == 0) {
        int col = w * 16 + l15;            // 0..63 (shared region, write once)
        #pragma unroll
        for (int r = 0; r < 4; ++r) {
            int row = b0 + quad * 4 + r;
            Tm[(size_t)row * 320 + col] = (_Float16)acc0[r];
        }
    } else {
        // A-half: job1 -> 64..127, job2 -> 128..191
        // B-half: job1 -> 256..319, job2 -> 192..255
        int colA = ((job == 1) ? 64 : 128) + w * 16 + l15;
        int colB = ((job == 1) ? 256 : 192) + w * 16 + l15;
        #pragma unroll
        for (int r = 0; r < 4; ++r) {
            int row = b0 + quad * 4 + r;
            Tm[(size_t)row * 320 + colA] = (_Float16)acc0[r];
            Tm[(size_t)row * 320 + colB] = (_Float16)acc1[r];
        }
    }
}

// ---------------------------------------------------------------------------
// Stage 2 v5: 32 rows x 128 cols per block, grid (256, 8) = 2048 blocks.
// Merged-T in LDS (21 KB, single array); epilogue x/h/c prefetched at kr top.
__global__ __launch_bounds__(256, 4) void s2_kernel(
    const _Float16* __restrict__ Tm, const _Float16* __restrict__ W2f,
    const float* __restrict__ cx, const float* __restrict__ ch,
    const float* __restrict__ bb,
    const float* __restrict__ x, const float* __restrict__ h,
    const float* __restrict__ c, float* __restrict__ out)
{
    __shared__ __align__(16) _Float16 TmSh[32][328];

    const int b0 = blockIdx.x * 32;
    const int by = blockIdx.y;             // 128-col slab: ctg = by*8+kr*4+w
    const int tid = threadIdx.x;
    const int w = tid >> 6, l = tid & 63, l15 = l & 15, quad = l >> 4;

    // stage merged-T tile (32 rows x 320): 1280 half8 chunks over 5 iters
    #pragma unroll
    for (int ii = 0; ii < 5; ++ii) {
        int i2 = tid + ii * 256;           // 0..1279
        int row = i2 / 40, c8 = i2 % 40;
        *(half8*)&TmSh[row][c8 * 8] = *(const half8*)&Tm[(size_t)(b0 + row) * 320 + c8 * 8];
    }
    __syncthreads();

    const size_t laneoff = (size_t)l * 8;

    #pragma unroll 1
    for (int kr = 0; kr < 2; ++kr) {
        const int ctg = by * 8 + kr * 4 + w;   // global col-tile 0..63
        const int k = ctg * 16 + l15;          // this lane's output column
        // --- epilogue prefetch: issue HBM loads before the MFMA chain ---
        float xv[2][4], hv[2][4], cv[2][4];
        #pragma unroll
        for (int rt = 0; rt < 2; ++rt)
            #pragma unroll
            for (int r = 0; r < 4; ++r) {
                size_t off = (size_t)(b0 + rt * 16 + quad * 4 + r) * 1024 + k;
                xv[rt][r] = x[off];
                hv[rt][r] = h[off];
                cv[rt][r] = c[off];
            }
        f32x4 acc[4][2] = {};                  // [sg][row-tile]
        const _Float16* bpi = W2f + (size_t)((0 * 64 + ctg) * 6) * 512 + laneoff;
        const _Float16* bpf = W2f + (size_t)((1 * 64 + ctg) * 6) * 512 + laneoff;
        const _Float16* bpo = W2f + (size_t)((2 * 64 + ctg) * 6) * 512 + laneoff;
        const _Float16* bpn = W2f + (size_t)((3 * 64 + ctg) * 6) * 512 + laneoff;
        #pragma unroll
        for (int ks = 0; ks < 6; ++ks) {
            half8 bi = *(const half8*)(bpi + (size_t)ks * 512);
            half8 bf = *(const half8*)(bpf + (size_t)ks * 512);
            half8 bo = *(const half8*)(bpo + (size_t)ks * 512);
            half8 bn = *(const half8*)(bpn + (size_t)ks * 512);
            const int aoff = ks * 32 + quad * 8;                       // A-half
            const int boff = ((ks < 2) ? ks * 32 : 128 + ks * 32) + quad * 8; // B-half
            #pragma unroll
            for (int rt = 0; rt < 2; ++rt) {
                half8 aA = *(const half8*)&TmSh[rt * 16 + l15][aoff];
                half8 aB = *(const half8*)&TmSh[rt * 16 + l15][boff];
                acc[0][rt] = __builtin_amdgcn_mfma_f32_16x16x32_f16(aA, bi, acc[0][rt], 0, 0, 0);
                acc[1][rt] = __builtin_amdgcn_mfma_f32_16x16x32_f16(aA, bf, acc[1][rt], 0, 0, 0);
                acc[2][rt] = __builtin_amdgcn_mfma_f32_16x16x32_f16(aB, bo, acc[2][rt], 0, 0, 0);
                acc[3][rt] = __builtin_amdgcn_mfma_f32_16x16x32_f16(aB, bn, acc[3][rt], 0, 0, 0);
            }
        }
        // fused elementwise epilogue (D: col=l15 -> k, row=quad*4+r -> batch)
        float cxi = cx[k], cxf = cx[1024 + k], cxo = cx[2048 + k], cxn = cx[3072 + k];
        float chi = ch[k], chf = ch[1024 + k], cho = ch[2048 + k], chn = ch[3072 + k];
        float bbi = bb[k], bbf = bb[1024 + k], bbo = bb[2048 + k], bbn = bb[3072 + k];
        #pragma unroll
        for (int rt = 0; rt < 2; ++rt) {
            #pragma unroll
            for (int r = 0; r < 4; ++r) {
                int row = b0 + rt * 16 + quad * 4 + r;
                size_t off = (size_t)row * 1024 + k;
                float pi = acc[0][rt][r] + xv[rt][r] * cxi + hv[rt][r] * chi + bbi;
                float pf = acc[1][rt][r] + xv[rt][r] * cxf + hv[rt][r] * chf + bbf;
                float po = acc[2][rt][r] + xv[rt][r] * cxo + hv[rt][r] * cho + bbo;
                float pn = acc[3][rt][r] + xv[rt][r] * cxn + hv[rt][r] * chn + bbn;
                // sigmoid/tanh via fast rcp (tolerance 0.115 >> rcp error)
                float ig = __builtin_amdgcn_rcpf(1.f + __expf(-pi));
                float fg = __builtin_amdgcn_rcpf(1.f + __expf(-pf));
                float og = __builtin_amdgcn_rcpf(1.f + __expf(-po));
                float ng = 1.f - 2.f * __builtin_amdgcn_rcpf(__expf(2.f * pn) + 1.f);
                float cn = fg * cv[rt][r] + ig * ng;
                float tc = 1.f - 2.f * __builtin_amdgcn_rcpf(__expf(2.f * cn) + 1.f);
                out[off] = og * tc;
                out[(size_t)8388608 + off] = cn;
            }
        }
    }
}

// ---------------------------------------------------------------------------
extern "C" void kernel_launch(void* const* d_in, const int* in_sizes, int n_in,
                              void* d_out, int out_size, void* d_ws, size_t ws_size,
                              hipStream_t stream)
{
    const float* x      = (const float*)d_in[0];
    const float* h      = (const float*)d_in[1];
    const float* c      = (const float*)d_in[2];
    const float* dia_x  = (const float*)d_in[3];
    const float* dia_h  = (const float*)d_in[4];
    const float* Ux     = (const float*)d_in[5];
    const float* Vx     = (const float*)d_in[6];
    const float* Uh0    = (const float*)d_in[7];
    const float* Vh0    = (const float*)d_in[8];
    const float* Uh1    = (const float*)d_in[9];
    const float* Vh1    = (const float*)d_in[10];
    const float* bias_x = (const float*)d_in[11];
    const float* bias_h = (const float*)d_in[12];
    float* out = (float*)d_out;

    char* ws = (char*)d_ws;
    _Float16* TmW  = (_Float16*)(ws + WS_TM);
    _Float16* U1f  = (_Float16*)(ws + WS_U1F);
    _Float16* Uh1f = (_Float16*)(ws + WS_UH1F);
    _Float16* W2f  = (_Float16*)(ws + WS_W2);
    float* cx = (float*)(ws + WS_CX);
    float* ch = (float*)(ws + WS_CH);
    float* bb = (float*)(ws + WS_BB);

    prep_kernel<<<1504, 256, 0, stream>>>(Ux, Vx, Uh0, Vh0, Uh1, Vh1,
                                          dia_x, dia_h, bias_x, bias_h,
                                          U1f, Uh1f, W2f, cx, ch, bb);
    s1_kernel<<<dim3(512, 3), 256, 0, stream>>>(x, h, U1f, Uh1f, TmW);
    s2_kernel<<<dim3(256, 8), 256, 0, stream>>>(TmW, W2f, cx, ch, bb,
                                                x, h, c, out);
}